// Round 8
// baseline (464.481 us; speedup 1.0000x reference)
//
#include <hip/hip_runtime.h>
#include <hip/hip_bf16.h>

// DeformBlock: B=4, C=256, H=W=128, BN=64, K=3.
// All convs via MFMA 16x16x32 bf16 (fp32 accum). Channel-last bf16
// activations; B-fragments pre-packed in ws lane order by k_prep.
//
// R1: k_deform conflict-free b128 phase B.  R3: k_down NaN fix.
// R4: k_up 64-px tiles + contiguous epilogue.  R6: k_deform LDS window.
// R7: fuse up+residual+stats+BN+SiLU into ONE persistent kernel with a
//     software grid barrier (grid=1024 = exact 4 blocks/CU co-residency;
//     LDS 37.9KB, launch_bounds(256,4) caps VGPR<=128). y kept in
//     registers across the barrier -> y written once (saves 134 MB
//     round-trip + k_stats/k_bn launches). All cross-block traffic via
//     device-scope __hip_atomic_* (XCD L2s not coherent).

typedef __attribute__((ext_vector_type(8))) short bf16x8;   // 8 bf16 = 4 VGPRs
typedef __attribute__((ext_vector_type(4))) short bf16x4;   // 8 B
typedef __attribute__((ext_vector_type(4))) float f32x4;

#define HW   16384
#define CC   256
#define BNC  64

// ws layout (bytes). Total required: ~24.2 MB.
#define WS_STATS   0          // 64 buckets * 512 f32 = 131072
#define WS_CNT     131072     // barrier counter (4 B)
#define WS_SSG     131136     // scale[256], shift[256] f32
#define WS_FD      135168     // wfrag_down: 4nt*8kk*512 bf16 = 32768
#define WS_FOM     167936     // wfrag_om:   2nt*18kk*512   = 36864
#define WS_FDEF    204800     // wfrag_def:  4nt*18kk*512   = 73728
#define WS_FUP     278528     // wfrag_up:   16nt*2kk*512   = 32768
#define WS_ZBF     311296     // z   [4][16384][64] bf16 = 8388608
#define WS_OM      8699904    // om  [4][16384][27] f32  = 7077888
#define WS_Z2      15777792   // z2  [4][16384][64] bf16 = 8388608

__device__ __forceinline__ short f2b(float f) {
    unsigned u = __float_as_uint(f);
    unsigned r = (u + 0x7FFFu + ((u >> 16) & 1u)) >> 16;   // RNE
    return (short)r;
}
__device__ __forceinline__ float b2f(short s) {
    return __uint_as_float(((unsigned)(unsigned short)s) << 16);
}

// ---------------- prep: pack all weight B-fragments (bf16, lane order) ----
__global__ void k_prep(const float* __restrict__ down_w, const float* __restrict__ off_w,
                       const float* __restrict__ mask_w, const float* __restrict__ def_w,
                       const float* __restrict__ up_w, char* __restrict__ ws) {
    int g = blockIdx.x * 256 + threadIdx.x;
    int row = g >> 6, lane = g & 63;
    if (row >= 172) return;
    int l15 = lane & 15, q = lane >> 4;
    short vals[8];
    short* dst;
    if (row < 32) {                       // down: K=256 over c
        int nt = row >> 3, kk = row & 7;
        int n = nt * 16 + l15;
        for (int j = 0; j < 8; ++j) {
            int c = kk * 32 + q * 8 + j;
            vals[j] = f2b(down_w[n * 256 + c]);
        }
        dst = (short*)(ws + WS_FD) + row * 512 + lane * 8;
    } else if (row < 68) {                // offmask: N=27 (pad 32), K=576, kappa=k*64+c
        int r = row - 32; int nt = r / 18, kk = r % 18;
        int n = nt * 16 + l15;
        for (int j = 0; j < 8; ++j) {
            int kap = kk * 32 + q * 8 + j; int k = kap >> 6, c = kap & 63;
            float v = 0.f;
            if (n < 18)      v = off_w[(n * 64 + c) * 9 + k];
            else if (n < 27) v = mask_w[((n - 18) * 64 + c) * 9 + k];
            vals[j] = f2b(v);
        }
        dst = (short*)(ws + WS_FOM) + r * 512 + lane * 8;
    } else if (row < 140) {               // def: N=64, K=576, u-permutation
        int r = row - 68; int nt = r / 18, kk = r % 18;
        int n = nt * 16 + l15;
        int u = kk * 4 + q, k = u >> 3;
        for (int j = 0; j < 8; ++j) {
            int c = (u & 7) * 8 + j;
            vals[j] = f2b(def_w[(n * 64 + c) * 9 + k]);
        }
        dst = (short*)(ws + WS_FDEF) + r * 512 + lane * 8;
    } else {                              // up: N=256, K=64
        int r = row - 140; int nt = r >> 1, kk = r & 1;
        int o = nt * 16 + l15;
        for (int j = 0; j < 8; ++j) {
            int c = kk * 32 + q * 8 + j;
            vals[j] = f2b(up_w[o * 64 + c]);
        }
        dst = (short*)(ws + WS_FUP) + r * 512 + lane * 8;
    }
    for (int j = 0; j < 8; ++j) dst[j] = vals[j];
}

// ---------------- down: z[b][hw][64] = x[b][c][hw] . W  (bf16 out) --------
__global__ __launch_bounds__(256) void k_down(const float* __restrict__ x,
                                              const short* __restrict__ wfd,
                                              short* __restrict__ zbf) {
    __shared__ __align__(16) short xl[64 * 264];  // [px][c=0..255], stride 264
    int blk = blockIdx.x;                  // 1024 blocks
    int b = blk >> 8;
    int hw0 = (blk & 255) * 64;
    int t = threadIdx.x;
    const float* xb = x + (size_t)b * CC * HW + hw0;
    int px = t & 63, w = t >> 6;
    for (int h = 0; h < 8; ++h) {          // stage ALL 256 channels: 8x b128/thread
        int c0 = h * 32 + w * 8;
        bf16x8 pk;
        #pragma unroll
        for (int j = 0; j < 8; ++j)
            pk[j] = f2b(xb[(size_t)(c0 + j) * HW + px]);
        *(bf16x8*)(&xl[px * 264 + c0]) = pk;   // dest 16B-aligned
    }
    __syncthreads();
    int lane = t & 63, wv = t >> 6;
    int l15 = lane & 15, q = lane >> 4;
    bf16x8 A[8];
    const short* xrow = &xl[(wv * 16 + l15) * 264];
    for (int kk = 0; kk < 8; ++kk)
        A[kk] = *(const bf16x8*)(xrow + kk * 32 + q * 8);
    const bf16x8* Bp = (const bf16x8*)wfd;
    size_t obase = ((size_t)b * HW + hw0 + wv * 16) * 64;
    for (int nt = 0; nt < 4; ++nt) {
        f32x4 acc = {0.f, 0.f, 0.f, 0.f};
        for (int kk = 0; kk < 8; ++kk) {
            bf16x8 Bf = Bp[(nt * 8 + kk) * 64 + lane];
            acc = __builtin_amdgcn_mfma_f32_16x16x32_bf16(A[kk], Bf, acc, 0, 0, 0);
        }
        int n = nt * 16 + l15;
        for (int r = 0; r < 4; ++r) {
            int prow = q * 4 + r;          // D: row=(lane>>4)*4+reg, col=lane&15
            zbf[obase + (size_t)prow * 64 + n] = f2b(acc[r]);
        }
    }
}

// ---------------- offmask: 3x3 conv, 27 outputs, A-frags direct from z ----
__global__ __launch_bounds__(256) void k_offmask(const short* __restrict__ zbf,
                                                 const short* __restrict__ wfom,
                                                 const float* __restrict__ off_b,
                                                 const float* __restrict__ mask_b,
                                                 float* __restrict__ om) {
    int blk = blockIdx.x;                  // 1024 blocks (64-px tiles, row-aligned)
    int b = blk >> 8;
    int hw0 = (blk & 255) * 64;
    int y = hw0 >> 7, x0 = hw0 & 127;
    int t = threadIdx.x, lane = t & 63, wv = t >> 6;
    int l15 = lane & 15, q = lane >> 4;
    int xx0 = x0 + wv * 16 + l15;
    const short* zb = zbf + (size_t)b * HW * 64;
    f32x4 acc0 = {0, 0, 0, 0}, acc1 = {0, 0, 0, 0};
    const bf16x8* Bp = (const bf16x8*)wfom;
    for (int kk = 0; kk < 18; ++kk) {
        int k = kk >> 1;
        int yy = y + (k / 3) - 1;
        int xx = xx0 + (k % 3) - 1;
        int c0 = (kk & 1) * 32 + q * 8;
        bf16x8 A = {0, 0, 0, 0, 0, 0, 0, 0};
        if (yy >= 0 && yy < 128 && xx >= 0 && xx < 128)
            A = *(const bf16x8*)(zb + ((size_t)(yy * 128 + xx)) * 64 + c0);
        bf16x8 B0 = Bp[kk * 64 + lane];
        bf16x8 B1 = Bp[(18 + kk) * 64 + lane];
        acc0 = __builtin_amdgcn_mfma_f32_16x16x32_bf16(A, B0, acc0, 0, 0, 0);
        acc1 = __builtin_amdgcn_mfma_f32_16x16x32_bf16(A, B1, acc1, 0, 0, 0);
    }
    float* omb = om + ((size_t)b * HW + hw0 + wv * 16) * 27;
    for (int half = 0; half < 2; ++half) {
        f32x4 acc = half ? acc1 : acc0;
        int n = half * 16 + l15;
        if (n < 27) {
            for (int r = 0; r < 4; ++r) {
                int prow = q * 4 + r;
                float v = acc[r];
                if (n < 18) v += off_b[n];
                else { v += mask_b[n - 18]; v = 1.f / (1.f + __expf(-v)); }
                omb[prow * 27 + n] = v;
            }
        }
    }
}

// ---------------- deform: LDS-staged bilinear gather -> valA -> MFMA ------
__global__ __launch_bounds__(256) void k_deform(const short* __restrict__ zbf,
                                                const float* __restrict__ om,
                                                const short* __restrict__ wfdef,
                                                const float* __restrict__ def_b,
                                                short* __restrict__ z2) {
    __shared__ __align__(16) short ldsZ[169 * 64];     // 13x13 px window, 21632 B
    __shared__ int4   pAi4[144];
    __shared__ float4 pAw4[144];
    __shared__ int    pAf[144];
    __shared__ __align__(16) short valA[18 * 64 * 8];  // A-frags for 16 px, K=576
    int blk = blockIdx.x;                  // 4096 blocks: b * (32x32 4x4-tiles)
    int b = blk >> 10;
    int tile = blk & 1023;
    int yt = (tile >> 5) << 2, xt = (tile & 31) << 2;
    int sy0 = yt - 4; sy0 = sy0 < 0 ? 0 : (sy0 > 115 ? 115 : sy0);
    int sx0 = xt - 4; sx0 = sx0 < 0 ? 0 : (sx0 > 115 ? 115 : sx0);
    int t = threadIdx.x;
    const short* zbs = zbf + (size_t)b * HW * 64;
    // stage window: 13 rows x 13 px x 8 cg of 16B, coalesced, slot-rotated
    for (int u = t; u < 1352; u += 256) {
        int r = u / 104, rem = u - r * 104;
        int p = rem >> 3, cg = rem & 7;
        int gp = (sy0 + r) * 128 + sx0 + p;
        int lpix = r * 13 + p;
        int slot = (cg + lpix) & 7;
        *(int4*)(&ldsZ[lpix * 64 + slot * 8]) = *(const int4*)(zbs + (size_t)gp * 64 + cg * 8);
    }
    if (t < 144) {                         // phase A: sampling params
        int px = t / 9, k = t % 9;
        int oy = yt + (px >> 2), ox = xt + (px & 3);
        const float* p = om + ((size_t)b * HW + oy * 128 + ox) * 27;
        float dy = p[2 * k], dx = p[2 * k + 1], m = p[18 + k];
        float py  = (float)oy + (float)(k / 3 - 1) + dy;
        float pxf = (float)ox + (float)(k % 3 - 1) + dx;
        float fy = floorf(py), fx = floorf(pxf);
        int iy = (int)fy, ix = (int)fx;
        float wy = py - fy, wx = pxf - fx;
        float ww[4] = { (1.f - wy) * (1.f - wx) * m, (1.f - wy) * wx * m,
                        wy * (1.f - wx) * m,          wy * wx * m };
        bool flg = (iy >= sy0) && (iy + 1 <= sy0 + 12) && (ix >= sx0) && (ix + 1 <= sx0 + 12);
        int ys[2] = {iy, iy + 1}, xs[2] = {ix, ix + 1};
        int   ri[4]; float rw[4];
        for (int ci = 0; ci < 4; ++ci) {
            int cy = ys[ci >> 1], cx = xs[ci & 1];
            if (flg) {                     // in-window => in-image, weight = ww
                int lp = (cy - sy0) * 13 + (cx - sx0);
                ri[ci] = (lp << 6) | (lp & 7);          // packed LDS base + rot key
                rw[ci] = ww[ci];
            } else {
                bool v = (cy >= 0 && cy < 128 && cx >= 0 && cx < 128);
                ri[ci] = v ? (cy * 128 + cx) * 64 : 0;  // global short-offset
                rw[ci] = v ? ww[ci] : 0.f;
            }
        }
        pAi4[t] = make_int4(ri[0], ri[1], ri[2], ri[3]);
        pAw4[t] = make_float4(rw[0], rw[1], rw[2], rw[3]);
        pAf[t]  = flg ? 1 : 0;
    }
    __syncthreads();
    // phase B: subtask s = u*16+px, u = kk*4+q; k = u>>3, cg = u&7.
    for (int it = 0; it < 5; ++it) {
        int s = t + it * 256;
        if (s < 1152) {
            int px = s & 15, u = s >> 4;
            int k = u >> 3, cg = u & 7;
            int task = px * 9 + k;
            int4   idx = pAi4[task];
            float4 wt  = pAw4[task];
            int    flg = pAf[task];
            int   ii[4] = { idx.x, idx.y, idx.z, idx.w };
            float wwt[4] = { wt.x, wt.y, wt.z, wt.w };
            int cgs = cg * 8;
            float acc[8] = {0.f, 0.f, 0.f, 0.f, 0.f, 0.f, 0.f, 0.f};
            #pragma unroll
            for (int ci = 0; ci < 4; ++ci) {
                float w = wwt[ci];
                int4 d;
                if (flg) {
                    int v = ii[ci];
                    d = *(const int4*)(&ldsZ[(v & ~63) + (((cg + (v & 7)) & 7) << 3)]);
                } else {
                    d = *(const int4*)(zbs + ii[ci] + cgs);
                }
                int dp[4] = { d.x, d.y, d.z, d.w };
                #pragma unroll
                for (int p = 0; p < 4; ++p) {
                    float lo = __uint_as_float((unsigned)dp[p] << 16);
                    float hi = __uint_as_float((unsigned)dp[p] & 0xffff0000u);
                    acc[2 * p]     += w * lo;
                    acc[2 * p + 1] += w * hi;
                }
            }
            bf16x8 out;
            #pragma unroll
            for (int j = 0; j < 8; ++j) out[j] = f2b(acc[j]);
            *(bf16x8*)(&valA[s * 8]) = out;   // conflict-free b128
        }
    }
    __syncthreads();
    int lane = t & 63, wv = t >> 6;
    int l15 = lane & 15, q = lane >> 4;
    f32x4 acc = {0, 0, 0, 0};
    const bf16x8* Bp = (const bf16x8*)wfdef;
    const bf16x8* Ap = (const bf16x8*)valA;
    for (int kk = 0; kk < 18; ++kk) {      // phase C: GEMM, wave = n-tile
        bf16x8 A  = Ap[kk * 64 + lane];
        bf16x8 Bf = Bp[(wv * 18 + kk) * 64 + lane];
        acc = __builtin_amdgcn_mfma_f32_16x16x32_bf16(A, Bf, acc, 0, 0, 0);
    }
    int n = wv * 16 + l15;
    float bias = def_b[n];
    short* z2b = z2 + (size_t)b * HW * 64;
    for (int r = 0; r < 4; ++r) {
        int prow = q * 4 + r;              // prow = px = (ly<<2)|lx
        int hw = (yt + (prow >> 2)) * 128 + xt + (prow & 3);
        z2b[(size_t)hw * 64 + n] = f2b(acc[r] + bias);
    }
}

// ------- fused up + residual + batch-stats + grid-barrier + BN + SiLU -----
// Grid MUST be 1024 blocks (= 4 blocks/CU x 256 CU co-resident; LDS 37.9KB,
// VGPR capped by launch_bounds(256,4)) or the soft barrier deadlocks.
__global__ __launch_bounds__(256, 4) void k_up(const short* __restrict__ z2,
                                               const short* __restrict__ wfup,
                                               const float* __restrict__ x,
                                               const float* __restrict__ gamma,
                                               const float* __restrict__ beta,
                                               float* __restrict__ yout,
                                               float* __restrict__ stats,
                                               unsigned* __restrict__ cnt,
                                               float* __restrict__ ssG) {
    __shared__ __align__(16) short yl[256 * 70];   // [o][px] bf16, 35840 B
    __shared__ float ssl[512];
    __shared__ int lflag;
    int blk = blockIdx.x;                  // 1024 blocks (64-px tiles)
    int b = blk >> 8;
    int hw0 = (blk & 255) * 64;
    int t = threadIdx.x, lane = t & 63, wv = t >> 6;
    int l15 = lane & 15, q = lane >> 4;
    const short* z2b = z2 + ((size_t)b * HW + hw0 + wv * 16) * 64;
    bf16x8 A0 = *(const bf16x8*)(z2b + (size_t)l15 * 64 + q * 8);
    bf16x8 A1 = *(const bf16x8*)(z2b + (size_t)l15 * 64 + 32 + q * 8);
    const bf16x8* Bp = (const bf16x8*)wfup;
    for (int nt = 0; nt < 16; ++nt) {
        f32x4 acc = {0, 0, 0, 0};
        acc = __builtin_amdgcn_mfma_f32_16x16x32_bf16(A0, Bp[(nt * 2 + 0) * 64 + lane], acc, 0, 0, 0);
        acc = __builtin_amdgcn_mfma_f32_16x16x32_bf16(A1, Bp[(nt * 2 + 1) * 64 + lane], acc, 0, 0, 0);
        int o = nt * 16 + l15;
        bf16x4 pk;
        #pragma unroll
        for (int r = 0; r < 4; ++r) pk[r] = f2b(acc[r]);   // px = q*4+r
        *(bf16x4*)(&yl[o * 70 + wv * 16 + q * 4]) = pk;    // 8B-aligned
    }
    __syncthreads();
    int i16 = t & 15, og = t >> 4;         // px0 = i16*4; o = og + 16*i
    int bucket = blk & 63;
    size_t base = (size_t)b * CC * HW + hw0 + (size_t)i16 * 4;
    float4 v[16];                          // y tile lives in registers across barrier
    #pragma unroll
    for (int i = 0; i < 16; ++i) {
        int o = og + 16 * i;
        size_t pb = base + (size_t)o * HW;
        float4 xv = *(const float4*)(x + pb);
        bf16x4 uv = *(const bf16x4*)(&yl[o * 70 + i16 * 4]);
        float v0 = b2f(uv[0]) + xv.x;
        float v1 = b2f(uv[1]) + xv.y;
        float v2 = b2f(uv[2]) + xv.z;
        float v3 = b2f(uv[3]) + xv.w;
        v[i] = make_float4(v0, v1, v2, v3);
        float s  = v0 + v1 + v2 + v3;
        float s2 = v0 * v0 + v1 * v1 + v2 * v2 + v3 * v3;
        #pragma unroll
        for (int m = 8; m >= 1; m >>= 1) { s += __shfl_xor(s, m); s2 += __shfl_xor(s2, m); }
        if (i16 == 0) {
            atomicAdd(&stats[bucket * 512 + o], s);
            atomicAdd(&stats[bucket * 512 + 256 + o], s2);
        }
    }
    __threadfence();                       // publish this block's stat adds
    __syncthreads();
    if (t == 0) {
        unsigned old = __hip_atomic_fetch_add(cnt, 1u, __ATOMIC_ACQ_REL, __HIP_MEMORY_SCOPE_AGENT);
        lflag = (old == 1023u) ? 1 : 0;
    }
    __syncthreads();
    if (lflag) {                           // last block reduces stats -> scale/shift
        float s = 0.f, s2 = 0.f;
        for (int u = 0; u < 64; ++u) {
            s  += __hip_atomic_load(&stats[u * 512 + t],       __ATOMIC_RELAXED, __HIP_MEMORY_SCOPE_AGENT);
            s2 += __hip_atomic_load(&stats[u * 512 + 256 + t], __ATOMIC_RELAXED, __HIP_MEMORY_SCOPE_AGENT);
        }
        float mean = s * (1.f / 65536.f);
        float var  = s2 * (1.f / 65536.f) - mean * mean;
        float rs = rsqrtf(var + 1e-5f);
        float sc = gamma[t] * rs;
        __hip_atomic_store(&ssG[t],       sc,                 __ATOMIC_RELAXED, __HIP_MEMORY_SCOPE_AGENT);
        __hip_atomic_store(&ssG[256 + t], beta[t] - mean * sc, __ATOMIC_RELAXED, __HIP_MEMORY_SCOPE_AGENT);
        __threadfence();
        __syncthreads();
        if (t == 0)
            __hip_atomic_fetch_add(cnt, 1u, __ATOMIC_ACQ_REL, __HIP_MEMORY_SCOPE_AGENT);
    }
    if (t == 0) {                          // wait for release (cnt == 1025)
        while (__hip_atomic_load(cnt, __ATOMIC_ACQUIRE, __HIP_MEMORY_SCOPE_AGENT) < 1025u)
            __builtin_amdgcn_s_sleep(2);
    }
    __syncthreads();
    ssl[t]       = __hip_atomic_load(&ssG[t],       __ATOMIC_RELAXED, __HIP_MEMORY_SCOPE_AGENT);
    ssl[256 + t] = __hip_atomic_load(&ssG[256 + t], __ATOMIC_RELAXED, __HIP_MEMORY_SCOPE_AGENT);
    __syncthreads();
    #pragma unroll
    for (int i = 0; i < 16; ++i) {         // BN + SiLU from registers, write once
        int o = og + 16 * i;
        float sc = ssl[o], sh = ssl[256 + o];
        size_t pb = base + (size_t)o * HW;
        float4 vv = v[i];
        float h0 = vv.x * sc + sh, h1 = vv.y * sc + sh;
        float h2 = vv.z * sc + sh, h3 = vv.w * sc + sh;
        *(float4*)(yout + pb) = make_float4(h0 / (1.f + __expf(-h0)),
                                            h1 / (1.f + __expf(-h1)),
                                            h2 / (1.f + __expf(-h2)),
                                            h3 / (1.f + __expf(-h3)));
    }
}

extern "C" void kernel_launch(void* const* d_in, const int* in_sizes, int n_in,
                              void* d_out, int out_size, void* d_ws, size_t ws_size,
                              hipStream_t stream) {
    const float* x      = (const float*)d_in[0];
    const float* down_w = (const float*)d_in[1];
    const float* off_w  = (const float*)d_in[2];
    const float* off_b  = (const float*)d_in[3];
    const float* mask_w = (const float*)d_in[4];
    const float* mask_b = (const float*)d_in[5];
    const float* def_w  = (const float*)d_in[6];
    const float* def_b  = (const float*)d_in[7];
    const float* up_w   = (const float*)d_in[8];
    const float* gamma  = (const float*)d_in[9];
    const float* beta   = (const float*)d_in[10];
    char* ws = (char*)d_ws;
    float*    stats = (float*)(ws + WS_STATS);
    unsigned* cnt   = (unsigned*)(ws + WS_CNT);
    float*    ssG   = (float*)(ws + WS_SSG);
    short* wfd   = (short*)(ws + WS_FD);
    short* wfom  = (short*)(ws + WS_FOM);
    short* wfdef = (short*)(ws + WS_FDEF);
    short* wfup  = (short*)(ws + WS_FUP);
    short* zbf   = (short*)(ws + WS_ZBF);
    float* om    = (float*)(ws + WS_OM);
    short* z2    = (short*)(ws + WS_Z2);
    float* y     = (float*)d_out;

    hipMemsetAsync(ws, 0, WS_FD, stream);  // zero stats + barrier counter + ss
    hipLaunchKernelGGL(k_prep,    dim3(43),   dim3(256), 0, stream, down_w, off_w, mask_w, def_w, up_w, ws);
    hipLaunchKernelGGL(k_down,    dim3(1024), dim3(256), 0, stream, x, wfd, zbf);
    hipLaunchKernelGGL(k_offmask, dim3(1024), dim3(256), 0, stream, zbf, wfom, off_b, mask_b, om);
    hipLaunchKernelGGL(k_deform,  dim3(4096), dim3(256), 0, stream, zbf, om, wfdef, def_b, z2);
    hipLaunchKernelGGL(k_up,      dim3(1024), dim3(256), 0, stream, z2, wfup, x, gamma, beta, y, stats, cnt, ssG);
}

// Round 9
// 239.747 us; speedup vs baseline: 1.9374x; 1.9374x over previous
//
#include <hip/hip_runtime.h>
#include <hip/hip_bf16.h>

// DeformBlock: B=4, C=256, H=W=128, BN=64, K=3.
// All convs via MFMA 16x16x32 bf16 (fp32 accum). Channel-last bf16
// activations; B-fragments pre-packed in ws lane order by k_prep.
//
// R1: k_deform conflict-free b128 phase B.  R3: k_down NaN fix.
// R4: k_up 64-px tiles + contiguous epilogue.  R6: k_deform LDS window.
// R7 FAILED (464us): grid soft-barrier costs ~250us on MI355X — device-
//     scope ACQ/REL + threadfence thrash non-coherent XCD L2s. REVERTED.
// R8: back to split k_up/k_stats/k_bn (R6 = 246us) + k_deform window
//     13x13 -> 11x11: LDS 45.5 -> ~39 KB lifts occupancy 2 -> 3-4
//     blocks/CU; fallback rate ~0.3% -> ~3% (offsets ~N(0,1)) is cheap.

typedef __attribute__((ext_vector_type(8))) short bf16x8;   // 8 bf16 = 4 VGPRs
typedef __attribute__((ext_vector_type(4))) short bf16x4;   // 8 B
typedef __attribute__((ext_vector_type(4))) float f32x4;

#define HW   16384
#define CC   256
#define BNC  64

// ws layout (bytes). Total required: ~24.2 MB.
#define WS_STATS   0          // 64 buckets * 512 f32 = 131072
#define WS_SS      131072     // scale[256], shift[256] f32
#define WS_FD      135168     // wfrag_down: 4nt*8kk*512 bf16 = 32768
#define WS_FOM     167936     // wfrag_om:   2nt*18kk*512   = 36864
#define WS_FDEF    204800     // wfrag_def:  4nt*18kk*512   = 73728
#define WS_FUP     278528     // wfrag_up:   16nt*2kk*512   = 32768
#define WS_ZBF     311296     // z   [4][16384][64] bf16 = 8388608
#define WS_OM      8699904    // om  [4][16384][27] f32  = 7077888
#define WS_Z2      15777792   // z2  [4][16384][64] bf16 = 8388608

__device__ __forceinline__ short f2b(float f) {
    unsigned u = __float_as_uint(f);
    unsigned r = (u + 0x7FFFu + ((u >> 16) & 1u)) >> 16;   // RNE
    return (short)r;
}
__device__ __forceinline__ float b2f(short s) {
    return __uint_as_float(((unsigned)(unsigned short)s) << 16);
}

// ---------------- prep: pack all weight B-fragments (bf16, lane order) ----
__global__ void k_prep(const float* __restrict__ down_w, const float* __restrict__ off_w,
                       const float* __restrict__ mask_w, const float* __restrict__ def_w,
                       const float* __restrict__ up_w, char* __restrict__ ws) {
    int g = blockIdx.x * 256 + threadIdx.x;
    int row = g >> 6, lane = g & 63;
    if (row >= 172) return;
    int l15 = lane & 15, q = lane >> 4;
    short vals[8];
    short* dst;
    if (row < 32) {                       // down: K=256 over c
        int nt = row >> 3, kk = row & 7;
        int n = nt * 16 + l15;
        for (int j = 0; j < 8; ++j) {
            int c = kk * 32 + q * 8 + j;
            vals[j] = f2b(down_w[n * 256 + c]);
        }
        dst = (short*)(ws + WS_FD) + row * 512 + lane * 8;
    } else if (row < 68) {                // offmask: N=27 (pad 32), K=576, kappa=k*64+c
        int r = row - 32; int nt = r / 18, kk = r % 18;
        int n = nt * 16 + l15;
        for (int j = 0; j < 8; ++j) {
            int kap = kk * 32 + q * 8 + j; int k = kap >> 6, c = kap & 63;
            float v = 0.f;
            if (n < 18)      v = off_w[(n * 64 + c) * 9 + k];
            else if (n < 27) v = mask_w[((n - 18) * 64 + c) * 9 + k];
            vals[j] = f2b(v);
        }
        dst = (short*)(ws + WS_FOM) + r * 512 + lane * 8;
    } else if (row < 140) {               // def: N=64, K=576, u-permutation
        int r = row - 68; int nt = r / 18, kk = r % 18;
        int n = nt * 16 + l15;
        int u = kk * 4 + q, k = u >> 3;
        for (int j = 0; j < 8; ++j) {
            int c = (u & 7) * 8 + j;
            vals[j] = f2b(def_w[(n * 64 + c) * 9 + k]);
        }
        dst = (short*)(ws + WS_FDEF) + r * 512 + lane * 8;
    } else {                              // up: N=256, K=64
        int r = row - 140; int nt = r >> 1, kk = r & 1;
        int o = nt * 16 + l15;
        for (int j = 0; j < 8; ++j) {
            int c = kk * 32 + q * 8 + j;
            vals[j] = f2b(up_w[o * 64 + c]);
        }
        dst = (short*)(ws + WS_FUP) + r * 512 + lane * 8;
    }
    for (int j = 0; j < 8; ++j) dst[j] = vals[j];
}

// ---------------- down: z[b][hw][64] = x[b][c][hw] . W  (bf16 out) --------
__global__ __launch_bounds__(256) void k_down(const float* __restrict__ x,
                                              const short* __restrict__ wfd,
                                              short* __restrict__ zbf) {
    __shared__ __align__(16) short xl[64 * 264];  // [px][c=0..255], stride 264
    int blk = blockIdx.x;                  // 1024 blocks
    int b = blk >> 8;
    int hw0 = (blk & 255) * 64;
    int t = threadIdx.x;
    const float* xb = x + (size_t)b * CC * HW + hw0;
    int px = t & 63, w = t >> 6;
    for (int h = 0; h < 8; ++h) {          // stage ALL 256 channels: 8x b128/thread
        int c0 = h * 32 + w * 8;
        bf16x8 pk;
        #pragma unroll
        for (int j = 0; j < 8; ++j)
            pk[j] = f2b(xb[(size_t)(c0 + j) * HW + px]);
        *(bf16x8*)(&xl[px * 264 + c0]) = pk;   // dest 16B-aligned
    }
    __syncthreads();
    int lane = t & 63, wv = t >> 6;
    int l15 = lane & 15, q = lane >> 4;
    bf16x8 A[8];
    const short* xrow = &xl[(wv * 16 + l15) * 264];
    for (int kk = 0; kk < 8; ++kk)
        A[kk] = *(const bf16x8*)(xrow + kk * 32 + q * 8);
    const bf16x8* Bp = (const bf16x8*)wfd;
    size_t obase = ((size_t)b * HW + hw0 + wv * 16) * 64;
    for (int nt = 0; nt < 4; ++nt) {
        f32x4 acc = {0.f, 0.f, 0.f, 0.f};
        for (int kk = 0; kk < 8; ++kk) {
            bf16x8 Bf = Bp[(nt * 8 + kk) * 64 + lane];
            acc = __builtin_amdgcn_mfma_f32_16x16x32_bf16(A[kk], Bf, acc, 0, 0, 0);
        }
        int n = nt * 16 + l15;
        for (int r = 0; r < 4; ++r) {
            int prow = q * 4 + r;          // D: row=(lane>>4)*4+reg, col=lane&15
            zbf[obase + (size_t)prow * 64 + n] = f2b(acc[r]);
        }
    }
}

// ---------------- offmask: 3x3 conv, 27 outputs, A-frags direct from z ----
__global__ __launch_bounds__(256) void k_offmask(const short* __restrict__ zbf,
                                                 const short* __restrict__ wfom,
                                                 const float* __restrict__ off_b,
                                                 const float* __restrict__ mask_b,
                                                 float* __restrict__ om) {
    int blk = blockIdx.x;                  // 1024 blocks (64-px tiles, row-aligned)
    int b = blk >> 8;
    int hw0 = (blk & 255) * 64;
    int y = hw0 >> 7, x0 = hw0 & 127;
    int t = threadIdx.x, lane = t & 63, wv = t >> 6;
    int l15 = lane & 15, q = lane >> 4;
    int xx0 = x0 + wv * 16 + l15;
    const short* zb = zbf + (size_t)b * HW * 64;
    f32x4 acc0 = {0, 0, 0, 0}, acc1 = {0, 0, 0, 0};
    const bf16x8* Bp = (const bf16x8*)wfom;
    for (int kk = 0; kk < 18; ++kk) {
        int k = kk >> 1;
        int yy = y + (k / 3) - 1;
        int xx = xx0 + (k % 3) - 1;
        int c0 = (kk & 1) * 32 + q * 8;
        bf16x8 A = {0, 0, 0, 0, 0, 0, 0, 0};
        if (yy >= 0 && yy < 128 && xx >= 0 && xx < 128)
            A = *(const bf16x8*)(zb + ((size_t)(yy * 128 + xx)) * 64 + c0);
        bf16x8 B0 = Bp[kk * 64 + lane];
        bf16x8 B1 = Bp[(18 + kk) * 64 + lane];
        acc0 = __builtin_amdgcn_mfma_f32_16x16x32_bf16(A, B0, acc0, 0, 0, 0);
        acc1 = __builtin_amdgcn_mfma_f32_16x16x32_bf16(A, B1, acc1, 0, 0, 0);
    }
    float* omb = om + ((size_t)b * HW + hw0 + wv * 16) * 27;
    for (int half = 0; half < 2; ++half) {
        f32x4 acc = half ? acc1 : acc0;
        int n = half * 16 + l15;
        if (n < 27) {
            for (int r = 0; r < 4; ++r) {
                int prow = q * 4 + r;
                float v = acc[r];
                if (n < 18) v += off_b[n];
                else { v += mask_b[n - 18]; v = 1.f / (1.f + __expf(-v)); }
                omb[prow * 27 + n] = v;
            }
        }
    }
}

// ---------------- deform: LDS-staged bilinear gather -> valA -> MFMA ------
// R6/R8: 4x4 px tile; stage 11x11 px z window in LDS; per-sample flag picks
// LDS gather (common, ~97%) vs global gather (outlier offsets).
__global__ __launch_bounds__(256) void k_deform(const short* __restrict__ zbf,
                                                const float* __restrict__ om,
                                                const short* __restrict__ wfdef,
                                                const float* __restrict__ def_b,
                                                short* __restrict__ z2) {
    __shared__ __align__(16) short ldsZ[121 * 64];     // 11x11 px window, 15488 B
    __shared__ int4   pAi4[144];
    __shared__ float4 pAw4[144];
    __shared__ int    pAf[144];
    __shared__ __align__(16) short valA[18 * 64 * 8];  // A-frags for 16 px, K=576
    int blk = blockIdx.x;                  // 4096 blocks: b * (32x32 4x4-tiles)
    int b = blk >> 10;
    int tile = blk & 1023;
    int yt = (tile >> 5) << 2, xt = (tile & 31) << 2;
    int sy0 = yt - 3; sy0 = sy0 < 0 ? 0 : (sy0 > 117 ? 117 : sy0);
    int sx0 = xt - 3; sx0 = sx0 < 0 ? 0 : (sx0 > 117 ? 117 : sx0);
    int t = threadIdx.x;
    const short* zbs = zbf + (size_t)b * HW * 64;
    // stage window: 11 rows x 11 px x 8 cg of 16B, coalesced, slot-rotated
    for (int u = t; u < 968; u += 256) {
        int r = u / 88, rem = u - r * 88;
        int p = rem >> 3, cg = rem & 7;
        int gp = (sy0 + r) * 128 + sx0 + p;
        int lpix = r * 11 + p;
        int slot = (cg + lpix) & 7;
        *(int4*)(&ldsZ[lpix * 64 + slot * 8]) = *(const int4*)(zbs + (size_t)gp * 64 + cg * 8);
    }
    if (t < 144) {                         // phase A: sampling params
        int px = t / 9, k = t % 9;
        int oy = yt + (px >> 2), ox = xt + (px & 3);
        const float* p = om + ((size_t)b * HW + oy * 128 + ox) * 27;
        float dy = p[2 * k], dx = p[2 * k + 1], m = p[18 + k];
        float py  = (float)oy + (float)(k / 3 - 1) + dy;
        float pxf = (float)ox + (float)(k % 3 - 1) + dx;
        float fy = floorf(py), fx = floorf(pxf);
        int iy = (int)fy, ix = (int)fx;
        float wy = py - fy, wx = pxf - fx;
        float ww[4] = { (1.f - wy) * (1.f - wx) * m, (1.f - wy) * wx * m,
                        wy * (1.f - wx) * m,          wy * wx * m };
        bool flg = (iy >= sy0) && (iy + 1 <= sy0 + 10) && (ix >= sx0) && (ix + 1 <= sx0 + 10);
        int ys[2] = {iy, iy + 1}, xs[2] = {ix, ix + 1};
        int   ri[4]; float rw[4];
        for (int ci = 0; ci < 4; ++ci) {
            int cy = ys[ci >> 1], cx = xs[ci & 1];
            if (flg) {                     // in-window => in-image, weight = ww
                int lp = (cy - sy0) * 11 + (cx - sx0);
                ri[ci] = (lp << 6) | (lp & 7);          // packed LDS base + rot key
                rw[ci] = ww[ci];
            } else {
                bool v = (cy >= 0 && cy < 128 && cx >= 0 && cx < 128);
                ri[ci] = v ? (cy * 128 + cx) * 64 : 0;  // global short-offset
                rw[ci] = v ? ww[ci] : 0.f;
            }
        }
        pAi4[t] = make_int4(ri[0], ri[1], ri[2], ri[3]);
        pAw4[t] = make_float4(rw[0], rw[1], rw[2], rw[3]);
        pAf[t]  = flg ? 1 : 0;
    }
    __syncthreads();
    // phase B: subtask s = u*16+px, u = kk*4+q; k = u>>3, cg = u&7.
    for (int it = 0; it < 5; ++it) {
        int s = t + it * 256;
        if (s < 1152) {
            int px = s & 15, u = s >> 4;
            int k = u >> 3, cg = u & 7;
            int task = px * 9 + k;
            int4   idx = pAi4[task];
            float4 wt  = pAw4[task];
            int    flg = pAf[task];
            int   ii[4] = { idx.x, idx.y, idx.z, idx.w };
            float wwt[4] = { wt.x, wt.y, wt.z, wt.w };
            int cgs = cg * 8;
            float acc[8] = {0.f, 0.f, 0.f, 0.f, 0.f, 0.f, 0.f, 0.f};
            #pragma unroll
            for (int ci = 0; ci < 4; ++ci) {
                float w = wwt[ci];
                int4 d;
                if (flg) {
                    int v = ii[ci];
                    d = *(const int4*)(&ldsZ[(v & ~63) + (((cg + (v & 7)) & 7) << 3)]);
                } else {
                    d = *(const int4*)(zbs + ii[ci] + cgs);
                }
                int dp[4] = { d.x, d.y, d.z, d.w };
                #pragma unroll
                for (int p = 0; p < 4; ++p) {
                    float lo = __uint_as_float((unsigned)dp[p] << 16);
                    float hi = __uint_as_float((unsigned)dp[p] & 0xffff0000u);
                    acc[2 * p]     += w * lo;
                    acc[2 * p + 1] += w * hi;
                }
            }
            bf16x8 out;
            #pragma unroll
            for (int j = 0; j < 8; ++j) out[j] = f2b(acc[j]);
            *(bf16x8*)(&valA[s * 8]) = out;   // conflict-free b128
        }
    }
    __syncthreads();
    int lane = t & 63, wv = t >> 6;
    int l15 = lane & 15, q = lane >> 4;
    f32x4 acc = {0, 0, 0, 0};
    const bf16x8* Bp = (const bf16x8*)wfdef;
    const bf16x8* Ap = (const bf16x8*)valA;
    for (int kk = 0; kk < 18; ++kk) {      // phase C: GEMM, wave = n-tile
        bf16x8 A  = Ap[kk * 64 + lane];
        bf16x8 Bf = Bp[(wv * 18 + kk) * 64 + lane];
        acc = __builtin_amdgcn_mfma_f32_16x16x32_bf16(A, Bf, acc, 0, 0, 0);
    }
    int n = wv * 16 + l15;
    float bias = def_b[n];
    short* z2b = z2 + (size_t)b * HW * 64;
    for (int r = 0; r < 4; ++r) {
        int prow = q * 4 + r;              // prow = px = (ly<<2)|lx
        int hw = (yt + (prow >> 2)) * 128 + xt + (prow & 3);
        z2b[(size_t)hw * 64 + n] = f2b(acc[r] + bias);
    }
}

// ---------------- up: y = x + up(z2), NCHW out, per-channel stats ---------
__global__ __launch_bounds__(256) void k_up(const short* __restrict__ z2,
                                            const short* __restrict__ wfup,
                                            const float* __restrict__ x,
                                            float* __restrict__ yout,
                                            float* __restrict__ stats) {
    __shared__ __align__(16) short yl[256 * 70];   // [o][px] bf16, 35840 B
    int blk = blockIdx.x;                  // 1024 blocks (64-px tiles)
    int b = blk >> 8;
    int hw0 = (blk & 255) * 64;
    int t = threadIdx.x, lane = t & 63, wv = t >> 6;
    int l15 = lane & 15, q = lane >> 4;
    const short* z2b = z2 + ((size_t)b * HW + hw0 + wv * 16) * 64;
    bf16x8 A0 = *(const bf16x8*)(z2b + (size_t)l15 * 64 + q * 8);
    bf16x8 A1 = *(const bf16x8*)(z2b + (size_t)l15 * 64 + 32 + q * 8);
    const bf16x8* Bp = (const bf16x8*)wfup;
    for (int nt = 0; nt < 16; ++nt) {
        f32x4 acc = {0, 0, 0, 0};
        acc = __builtin_amdgcn_mfma_f32_16x16x32_bf16(A0, Bp[(nt * 2 + 0) * 64 + lane], acc, 0, 0, 0);
        acc = __builtin_amdgcn_mfma_f32_16x16x32_bf16(A1, Bp[(nt * 2 + 1) * 64 + lane], acc, 0, 0, 0);
        int o = nt * 16 + l15;
        bf16x4 pk;
        #pragma unroll
        for (int r = 0; r < 4; ++r) pk[r] = f2b(acc[r]);   // px = q*4+r
        *(bf16x4*)(&yl[o * 70 + wv * 16 + q * 4]) = pk;    // 8B-aligned
    }
    __syncthreads();
    int i16 = t & 15, og = t >> 4;         // px0 = i16*4; o = og + 16*i
    int bucket = blk & 63;
    size_t base = (size_t)b * CC * HW + hw0 + (size_t)i16 * 4;
    #pragma unroll
    for (int i = 0; i < 16; ++i) {
        int o = og + 16 * i;
        size_t pb = base + (size_t)o * HW;
        float4 xv = *(const float4*)(x + pb);
        bf16x4 uv = *(const bf16x4*)(&yl[o * 70 + i16 * 4]);
        float v0 = b2f(uv[0]) + xv.x;
        float v1 = b2f(uv[1]) + xv.y;
        float v2 = b2f(uv[2]) + xv.z;
        float v3 = b2f(uv[3]) + xv.w;
        *(float4*)(yout + pb) = make_float4(v0, v1, v2, v3);
        float s  = v0 + v1 + v2 + v3;
        float s2 = v0 * v0 + v1 * v1 + v2 * v2 + v3 * v3;
        #pragma unroll
        for (int m = 8; m >= 1; m >>= 1) { s += __shfl_xor(s, m); s2 += __shfl_xor(s2, m); }
        if (i16 == 0) {
            atomicAdd(&stats[bucket * 512 + o], s);
            atomicAdd(&stats[bucket * 512 + 256 + o], s2);
        }
    }
}

// ---------------- stats reduce -> scale/shift -----------------------------
__global__ void k_stats(const float* __restrict__ stats, const float* __restrict__ gamma,
                        const float* __restrict__ beta, float* __restrict__ ss) {
    int o = threadIdx.x;                   // 256 threads, 1 block
    float s = 0.f, s2 = 0.f;
    for (int u = 0; u < 64; ++u) { s += stats[u * 512 + o]; s2 += stats[u * 512 + 256 + o]; }
    float mean = s * (1.f / 65536.f);
    float var  = s2 * (1.f / 65536.f) - mean * mean;
    float rs = rsqrtf(var + 1e-5f);
    float sc = gamma[o] * rs;
    ss[o]       = sc;
    ss[256 + o] = beta[o] - mean * sc;
}

// ---------------- BN apply + SiLU, in-place on d_out ----------------------
__global__ __launch_bounds__(256) void k_bn(float* __restrict__ y, const float* __restrict__ ss) {
    int g = blockIdx.x * 256 + threadIdx.x;            // 1,048,576 threads, 16 floats each
    int o = (g >> 10) & 255;                           // 1024 16-float chunks per plane
    float sc = ss[o], sh = ss[256 + o];
    float4* p = (float4*)y + (size_t)g * 4;
    for (int i = 0; i < 4; ++i) {
        float4 v = p[i];
        float vf[4] = { v.x, v.y, v.z, v.w };
        for (int j = 0; j < 4; ++j) {
            float h = vf[j] * sc + sh;
            vf[j] = h / (1.f + __expf(-h));            // SiLU
        }
        p[i] = make_float4(vf[0], vf[1], vf[2], vf[3]);
    }
}

extern "C" void kernel_launch(void* const* d_in, const int* in_sizes, int n_in,
                              void* d_out, int out_size, void* d_ws, size_t ws_size,
                              hipStream_t stream) {
    const float* x      = (const float*)d_in[0];
    const float* down_w = (const float*)d_in[1];
    const float* off_w  = (const float*)d_in[2];
    const float* off_b  = (const float*)d_in[3];
    const float* mask_w = (const float*)d_in[4];
    const float* mask_b = (const float*)d_in[5];
    const float* def_w  = (const float*)d_in[6];
    const float* def_b  = (const float*)d_in[7];
    const float* up_w   = (const float*)d_in[8];
    const float* gamma  = (const float*)d_in[9];
    const float* beta   = (const float*)d_in[10];
    char* ws = (char*)d_ws;
    float* stats = (float*)(ws + WS_STATS);
    float* ss    = (float*)(ws + WS_SS);
    short* wfd   = (short*)(ws + WS_FD);
    short* wfom  = (short*)(ws + WS_FOM);
    short* wfdef = (short*)(ws + WS_FDEF);
    short* wfup  = (short*)(ws + WS_FUP);
    short* zbf   = (short*)(ws + WS_ZBF);
    float* om    = (float*)(ws + WS_OM);
    short* z2    = (short*)(ws + WS_Z2);
    float* y     = (float*)d_out;

    hipMemsetAsync(stats, 0, 64 * 512 * sizeof(float), stream);
    hipLaunchKernelGGL(k_prep,    dim3(43),   dim3(256), 0, stream, down_w, off_w, mask_w, def_w, up_w, ws);
    hipLaunchKernelGGL(k_down,    dim3(1024), dim3(256), 0, stream, x, wfd, zbf);
    hipLaunchKernelGGL(k_offmask, dim3(1024), dim3(256), 0, stream, zbf, wfom, off_b, mask_b, om);
    hipLaunchKernelGGL(k_deform,  dim3(4096), dim3(256), 0, stream, zbf, om, wfdef, def_b, z2);
    hipLaunchKernelGGL(k_up,      dim3(1024), dim3(256), 0, stream, z2, wfup, x, y, stats);
    hipLaunchKernelGGL(k_stats,   dim3(1),    dim3(256), 0, stream, stats, gamma, beta, ss);
    hipLaunchKernelGGL(k_bn,      dim3(4096), dim3(256), 0, stream, y, ss);
}